// Round 11
// baseline (376.843 us; speedup 1.0000x reference)
//
#include <hip/hip_runtime.h>
#include <hip/hip_cooperative_groups.h>

namespace cg = cooperative_groups;

typedef unsigned long long u64;
typedef unsigned int u32;

#define R_TOT 159882
#define POST 1000
#define IMG_SZ 800.0f
#define NMS_TH 0.7f
#define BBOX_CLIP 4.135166556742356f
#define LCAP 1024
#define TRI_FULL 7680   // 64 * 120 words: packed lower-triangle (tr=1..15) per level
#define TRI_LDS  6720   // 64 * 105 words: tiles tr<=14 staged in LDS
#define NBLK 160

__device__ __forceinline__ float fadd_(float a, float b){ return __fadd_rn(a,b); }
__device__ __forceinline__ float fsub_(float a, float b){ return __fsub_rn(a,b); }
__device__ __forceinline__ float fmul_(float a, float b){ return __fmul_rn(a,b); }

__device__ __forceinline__ int lvl_len(int l){ const int L[5]={120000,30000,7500,1875,507}; return L[l]; }
__device__ __forceinline__ int lvl_off(int l){ const int L[5]={0,120000,150000,157500,159375}; return L[l]; }
__device__ __forceinline__ int lvl_k(int l){ const int L[5]={1000,1000,1000,1000,507}; return L[l]; }

__device__ __forceinline__ u32 mono_(u32 u){ return (u & 0x80000000u) ? ~u : (u | 0x80000000u); }

__device__ __forceinline__ u64 readlane64(u64 v, int i){
  u32 lo = (u32)__builtin_amdgcn_readlane((int)(u32)v, i);
  u32 hi = (u32)__builtin_amdgcn_readlane((int)(u32)(v >> 32), i);
  return ((u64)hi << 32) | (u64)lo;
}

__device__ __forceinline__ int lbound_(const u64* a, int n, u64 key){
  int lo = 0, hi = n;
  while (lo < hi){ int mid = (lo + hi) >> 1; if (a[mid] < key) lo = mid + 1; else hi = mid; }
  return lo;
}

// Workspace byte offsets
#define OFF_HIST16  0u         // 10*16*4096 int  -> 2621440
#define OFF_BSTAR   2621440u
#define OFF_REM     2621696u
#define OFF_CNTG    2621952u
#define OFF_CNT2    2622208u
#define OFF_MAING   2622464u   // 10*1024 u64 -> 2704384
#define OFF_LBUFG   2704384u   // 10*1024 u64 -> 2786304
#define OFF_BOXL    2786304u   // 10*1024 f4  -> 2950144
#define OFF_SCORE   2950144u   // 10*1024 f32 -> 2991104
#define OFF_OKEYN   2991104u   // 10*1024 u64 -> 3073024
#define OFF_NBOX    3073024u   // 10*1024 f4  -> 3236864
#define OFF_LTG     3236864u   // 10*7680 u64 -> 3851264
#define OFF_DIAGF   3851264u   // 10*1024 u64 -> 3933184
#define OFF_KEPTW   3933184u   // 10*16 u64   -> 3934464
#define OFF_NCNT    3934464u   // 10 int

// One cooperative kernel; phases = R9's proven pipeline, launches -> grid.sync().
// (R10 lesson: never collapse the mask's parallelism into 10 blocks.)
__global__ __launch_bounds__(256) void k_all(const float* __restrict__ obj,
                                             const float4* __restrict__ deltas,
                                             const float4* __restrict__ anchors,
                                             float* __restrict__ out,
                                             char* __restrict__ ws){
  int* hist16   = (int*)(ws + OFF_HIST16);
  int* bstarG   = (int*)(ws + OFF_BSTAR);
  int* remG     = (int*)(ws + OFF_REM);
  int* cntg     = (int*)(ws + OFF_CNTG);
  int* cnt2     = (int*)(ws + OFF_CNT2);
  u64* mainG    = (u64*)(ws + OFF_MAING);
  u64* LbufG    = (u64*)(ws + OFF_LBUFG);
  float4* boxL  = (float4*)(ws + OFF_BOXL);
  float* scoreL = (float*)(ws + OFF_SCORE);
  u64* okeyN    = (u64*)(ws + OFF_OKEYN);
  float4* nboxG = (float4*)(ws + OFF_NBOX);
  u64* LTG      = (u64*)(ws + OFF_LTG);
  u64* diagF    = (u64*)(ws + OFF_DIAGF);
  u64* keptW    = (u64*)(ws + OFF_KEPTW);
  int* ncnt     = (int*)(ws + OFF_NCNT);

  __shared__ u64 SH[7744];     // 61.9 KB union: lh/hsum | seldecode bufs | LT+dFL | runs
  __shared__ u64 KwS[16];
  __shared__ u64 validW[16];
  __shared__ int wsum4[4];
  __shared__ int h16s[16];
  __shared__ int cl[5];
  __shared__ int sh_sc, sh_rem;
  __shared__ u64 sh_thr;

  cg::grid_group grid = cg::this_grid();
  int bid = blockIdx.x, tid = threadIdx.x, lane = tid & 63, wid = tid >> 6;

  // ---------- Phase A: per-slice 12-bit histogram (overwrite, no memset) ----------
  {
    int g = bid >> 4, sl = bid & 15;
    int img = g/5, lvl = g%5;
    int n = lvl_len(lvl), s0 = lvl_off(lvl);
    int* lh = (int*)SH;
    for (int i = tid; i < 4096; i += 256) lh[i] = 0;
    __syncthreads();
    int lo = (int)((long long)n * sl / 16), hiS = (int)((long long)n * (sl+1) / 16);
    const float* p = obj + img*R_TOT + s0;
    #pragma unroll 4
    for (int e = lo + tid; e < hiS; e += 256){
      u32 mu = mono_(__float_as_uint(p[e]));
      atomicAdd(&lh[(~mu) >> 20], 1);
    }
    __syncthreads();
    int* dst = hist16 + (g*16 + sl)*4096;
    for (int i = tid; i < 4096; i += 256) dst[i] = lh[i];
  }
  grid.sync();

  // ---------- Phase B: sum slices + pick the k-th bin (blocks 0..9) ----------
  if (bid < 10){
    int g = bid, lvl = g % 5, k = lvl_k(lvl);
    int* hsum = (int*)SH;
    const int* hb = hist16 + g*16*4096;
    for (int i = tid; i < 4096; i += 256){
      int s = 0;
      #pragma unroll
      for (int sl = 0; sl < 16; sl++) s += hb[sl*4096 + i];
      hsum[i] = s;
    }
    __syncthreads();
    int base = tid*16;
    int hh[16]; int part = 0;
    #pragma unroll
    for (int q = 0; q < 16; q++){ hh[q] = hsum[base + q]; part += hh[q]; }
    int x = part;
    for (int d = 1; d < 64; d <<= 1){ int y = __shfl_up(x, d); if (lane >= d) x += y; }
    if (lane == 63) wsum4[wid] = x;
    __syncthreads();
    int add = 0;
    for (int w = 0; w < wid; w++) add += wsum4[w];
    int incl = x + add, excl = incl - part;
    if (excl < k && k <= incl){
      int cum = excl;
      #pragma unroll
      for (int q = 0; q < 16; q++){
        if (cum + hh[q] >= k){ bstarG[g] = base + q; remG[g] = k - cum; break; }
        cum += hh[q];
      }
    }
    if (tid == 0){ cntg[g] = 0; cnt2[g] = 0; }
  }
  grid.sync();

  // ---------- Phase C: wide collect scan ----------
  {
    int g = bid >> 4, sl = bid & 15;
    int img = g/5, lvl = g%5;
    int n = lvl_len(lvl), s0 = lvl_off(lvl);
    int lo = (int)((long long)n * sl / 16), hiS = (int)((long long)n * (sl+1) / 16);
    const float* p = obj + img*R_TOT + s0;
    int bs = bstarG[g];
    #pragma unroll 8
    for (int e = lo + tid; e < hiS; e += 256){
      u32 mu = mono_(__float_as_uint(p[e]));
      u64 key56 = (((u64)(~mu)) << 24) | (u32)(s0 + e);
      int bin = (int)(key56 >> 44);
      if (bin < bs){ int pos = atomicAdd(&cntg[g], 1); mainG[g*1024 + pos] = key56; }
      else if (bin == bs){ int pos = atomicAdd(&cnt2[g], 1); if (pos < LCAP) LbufG[g*LCAP + pos] = key56; }
    }
  }
  grid.sync();

  // ---------- Phase D: tie-resolve + sort + decode + valid-compaction (blocks 0..9) ----------
  if (bid < 10){
    int g = bid, img = g/5, lvl = g%5;
    int s0 = lvl_off(lvl), n = lvl_len(lvl), k = lvl_k(lvl);
    const float* p = obj + img*R_TOT + s0;
    u64* mainL = SH;
    u64* Lbuf  = SH + 1024;
    u64* lokey = SH + 2048;
    float4* lbox = (float4*)(SH + 3072);
    int nb = cntg[g], c2 = cnt2[g], rem = remG[g], bs = bstarG[g];
    for (int i = tid; i < 1024; i += 256) mainL[i] = (i < nb) ? mainG[g*1024 + i] : ~0ull;
    int c2c = c2 < LCAP ? c2 : LCAP;
    for (int e = tid; e < c2c; e += 256) Lbuf[e] = LbufG[g*LCAP + e];
    if (tid == 0){ sh_sc = 0; sh_rem = rem; }
    __syncthreads();
    if (c2 <= LCAP){
      for (int e = tid; e < c2; e += 256){
        u64 kk = Lbuf[e];
        int rk = 0;
        for (int q = 0; q < c2; q++) rk += (Lbuf[q] < kk) ? 1 : 0;
        if (rk < rem){ int p2 = atomicAdd(&sh_sc, 1); mainL[nb + p2] = kk; }
      }
    } else {
      if (tid == 0) sh_thr = ((u64)bs) << 44;
      __syncthreads();
      for (int shift = 40; shift >= 0; shift -= 4){
        if (tid < 16) h16s[tid] = 0;
        __syncthreads();
        u64 pref = sh_thr;
        u64 himask = ~((1ull << (shift+4)) - 1ull);
        for (int e = tid; e < n; e += 256){
          u32 mu = mono_(__float_as_uint(p[e]));
          u64 kk = (((u64)(~mu)) << 24) | (u32)(s0 + e);
          if ((kk & himask) == (pref & himask)) atomicAdd(&h16s[(int)((kk >> shift) & 15)], 1);
        }
        __syncthreads();
        if (tid == 0){
          int r2 = sh_rem, cum = 0;
          for (int d = 0; d < 16; d++){
            int hb2 = h16s[d];
            if (cum + hb2 >= r2){ sh_thr = pref | ((u64)d << shift); sh_rem = r2 - cum; break; }
            cum += hb2;
          }
        }
        __syncthreads();
      }
      u64 thr = sh_thr;
      for (int e = tid; e < n; e += 256){
        u32 mu = mono_(__float_as_uint(p[e]));
        u64 kk = (((u64)(~mu)) << 24) | (u32)(s0 + e);
        if ((int)(kk >> 44) == bs && kk <= thr){ int p2 = atomicAdd(&sh_sc, 1); mainL[nb + p2] = kk; }
      }
    }
    __syncthreads();
    for (int k2 = 2; k2 <= 1024; k2 <<= 1){
      for (int j = k2 >> 1; j > 0; j >>= 1){
        __syncthreads();
        for (int i = tid; i < 1024; i += 256){
          int ixj = i ^ j;
          if (ixj > i){
            u64 a = mainL[i], b = mainL[ixj];
            bool up = (i & k2) == 0;
            if ((a > b) == up){ mainL[i] = b; mainL[ixj] = a; }
          }
        }
      }
    }
    __syncthreads();
    for (int it = 0; it < 4; it++){
      int r = it*256 + tid;
      bool validF = false;
      if (r < k){
        int idx = (int)(mainL[r] & 0xFFFFFFu);
        float4 a = anchors[idx];
        float4 d = deltas[img*R_TOT + idx];
        float o = obj[img*R_TOT + idx];
        float wa = fsub_(a.z, a.x), ha = fsub_(a.w, a.y);
        float cxa = fadd_(a.x, fmul_(0.5f, wa)), cya = fadd_(a.y, fmul_(0.5f, ha));
        float dw = fminf(d.z, BBOX_CLIP), dh = fminf(d.w, BBOX_CLIP);
        float cx = fadd_(fmul_(d.x, wa), cxa), cy = fadd_(fmul_(d.y, ha), cya);
        float w  = fmul_(expf(dw), wa),        h  = fmul_(expf(dh), ha);
        float x1 = fsub_(cx, fmul_(0.5f, w)), y1 = fsub_(cy, fmul_(0.5f, h));
        float x2 = fadd_(cx, fmul_(0.5f, w)), y2 = fadd_(cy, fmul_(0.5f, h));
        x1 = fminf(fmaxf(x1, 0.0f), IMG_SZ); y1 = fminf(fmaxf(y1, 0.0f), IMG_SZ);
        x2 = fminf(fmaxf(x2, 0.0f), IMG_SZ); y2 = fminf(fmaxf(y2, 0.0f), IMG_SZ);
        validF = (fsub_(x2, x1) >= 1e-3f) && (fsub_(y2, y1) >= 1e-3f);
        float e = expf(-o);
        float sig = __fdiv_rn(1.0f, fadd_(1.0f, e));
        float s = validF ? sig : -1.0f;
        u32 sb = __float_as_uint(s);
        u32 ms = (sb & 0x80000000u) ? ~sb : (sb | 0x80000000u);
        float4 b4 = make_float4(x1, y1, x2, y2);
        boxL[g*1024 + r] = b4;
        scoreL[g*1024 + r] = sig;
        lokey[r] = (((u64)(~ms)) << 32) | (u32)(lvl*1000 + r);
        lbox[r] = b4;
      }
      validW[it*4 + wid] = __ballot(validF);
    }
    __syncthreads();
    if (tid < 64){
      int cnt = 0;
      float off = (float)lvl * 801.0f;
      #pragma unroll
      for (int w = 0; w < 16; w++){
        u64 mask = validW[w];
        int r2 = w*64 + tid;
        bool v = (mask >> tid) & 1ull;
        int before = __popcll(mask & ((1ull << tid) - 1ull));
        if (v){
          int pos = cnt + before;
          float4 b = lbox[r2];
          nboxG[g*1024 + pos] = make_float4(fadd_(b.x,off), fadd_(b.y,off), fadd_(b.z,off), fadd_(b.w,off));
          okeyN[g*1024 + pos] = lokey[r2];
        }
        cnt += __popcll(mask);
      }
      if (tid == 0) ncnt[g] = cnt;
    }
  }
  grid.sync();

  // ---------- Phase E: IoU bitmask tiles (1360 tiles over 640 waves) ----------
  {
    int gwid = bid*4 + wid;
    for (int t = gwid; t < 1360; t += NBLK*4){
      int g = t / 136, rem2 = t - g*136;
      int tr = 0;
      while (((tr+1)*(tr+2))/2 <= rem2) tr++;
      int tw = rem2 - (tr*(tr+1))/2;
      int m = ncnt[g];
      if (tr*64 >= m) continue;
      int j = tr*64 + lane;
      float4 a = (j < m) ? nboxG[g*1024 + j] : make_float4(0,0,0,0);
      float areaA = fmul_(fsub_(a.z,a.x), fsub_(a.w,a.y));
      int imax = m - tw*64; if (imax > 64) imax = 64;
      const float4* cb = nboxG + g*1024 + tw*64;
      if (tw == tr){
        u64 bitsF = 0;
        for (int ii = lane+1; ii < imax; ii++){
          float4 b = cb[ii];
          float ltx = fmaxf(a.x, b.x), lty = fmaxf(a.y, b.y);
          float rbx = fminf(a.z, b.z), rby = fminf(a.w, b.w);
          float wx = fmaxf(fsub_(rbx, ltx), 0.0f), wy = fmaxf(fsub_(rby, lty), 0.0f);
          float inter = fmul_(wx, wy);
          float areaB = fmul_(fsub_(b.z,b.x), fsub_(b.w,b.y));
          float den = fadd_(fsub_(fadd_(areaA, areaB), inter), 1e-9f);
          if (__fdiv_rn(inter, den) > NMS_TH) bitsF |= (1ull << ii);
        }
        if (j < m) diagF[g*1024 + j] = bitsF;
      } else {
        u64 bits = 0;
        #pragma unroll 4
        for (int ii = 0; ii < imax; ii++){
          float4 b = cb[ii];
          float ltx = fmaxf(a.x, b.x), lty = fmaxf(a.y, b.y);
          float rbx = fminf(a.z, b.z), rby = fminf(a.w, b.w);
          float wx = fmaxf(fsub_(rbx, ltx), 0.0f), wy = fmaxf(fsub_(rby, lty), 0.0f);
          float inter = fmul_(wx, wy);
          float areaB = fmul_(fsub_(b.z,b.x), fsub_(b.w,b.y));
          float den = fadd_(fsub_(fadd_(areaA, areaB), inter), 1e-9f);
          if (__fdiv_rn(inter, den) > NMS_TH) bits |= (1ull << ii);
        }
        if (j < m) LTG[(size_t)g*TRI_FULL + ((tr*(tr-1))/2 + tw)*64 + lane] = bits;
      }
    }
  }
  grid.sync();

  // ---------- Phase F: greedy scan from LDS-staged triangle (blocks 0..9) ----------
  if (bid < 10){
    int g = bid;
    u64* LT = SH;
    u64* dFL = SH + TRI_LDS;
    int m = ncnt[g];
    for (int i = tid; i < TRI_LDS; i += 256) LT[i] = LTG[(size_t)g*TRI_FULL + i];
    for (int i = tid; i < 1024; i += 256) dFL[i] = diagF[g*1024 + i];
    if (tid < 16) KwS[tid] = 0;
    __syncthreads();
    if (tid < 64){
      int nch = (m + 63) >> 6;
      for (int c = 0; c < nch; c++){
        int row = c*64 + lane;
        bool inr = row < m;
        u64 supp = 0;
        if (c < 15){
          int tb = (c*(c-1))/2;
          for (int q = 0; q < c; q++) supp |= LT[(tb+q)*64 + lane] & KwS[q];
        } else {
          const u64* gp = LTG + (size_t)g*TRI_FULL + 105*64;
          #pragma unroll
          for (int q = 0; q < 15; q++) supp |= gp[q*64 + lane] & KwS[q];
        }
        u64 fwd = inr ? dFL[row] : 0;
        u64 live = __ballot(inr && (supp == 0));
        u64 fz = __ballot(fwd != 0);
        u64 kept = 0;
        while (live){
          if (!(live & fz)){ kept |= live; break; }
          int i = __builtin_ctzll(live);
          kept |= (1ull << i);
          live &= ~(1ull << i);
          live &= ~readlane64(fwd, i);
        }
        KwS[c] = kept;
        if (lane == 0) keptW[g*16 + c] = kept;
      }
    }
  }
  grid.sync();

  // ---------- Phase G: merge + output (blocks 0..1) ----------
  if (bid < 2){
    int img = bid;
    u64* runs = SH;   // 5*1024
    if (tid < 5) cl[tid] = 0;
    __syncthreads();
    for (int l = wid; l < 5; l += 4){
      int g = img*5 + l;
      int m = ncnt[g];
      int nch = (m + 63) >> 6;
      int cnt = 0;
      for (int c = 0; c < nch; c++){
        u64 w = keptW[g*16 + c];
        bool kp = (w >> lane) & 1ull;
        int before = __popcll(w & ((1ull << lane) - 1ull));
        if (kp) runs[l*1024 + cnt + before] = okeyN[g*1024 + c*64 + lane];
        cnt += __popcll(w);
      }
      if (lane == 0) cl[l] = cnt;
    }
    __syncthreads();
    for (int t = tid; t < POST; t += 256){
      out[img*POST*4 + t*4 + 0] = 0.0f;
      out[img*POST*4 + t*4 + 1] = 0.0f;
      out[img*POST*4 + t*4 + 2] = 0.0f;
      out[img*POST*4 + t*4 + 3] = 0.0f;
      out[2*POST*4 + img*POST + t] = -1.0f;
    }
    __syncthreads();
    for (int idx = tid; idx < 5*1024; idx += 256){
      int l = idx >> 10, i = idx & 1023;
      if (i < cl[l]){
        u64 key = runs[l*1024 + i];
        int rank = i;
        #pragma unroll
        for (int l2 = 0; l2 < 5; l2++)
          if (l2 != l) rank += lbound_(runs + l2*1024, cl[l2], key);
        if (rank < POST){
          int pos = (int)(key & 0xFFFFFFFFull);
          int lvl = pos / 1000, r = pos - lvl*1000;
          int gg = img*5 + lvl;
          float4 bo = boxL[gg*1024 + r];
          float sc = scoreL[gg*1024 + r];
          out[img*POST*4 + rank*4 + 0] = bo.x;
          out[img*POST*4 + rank*4 + 1] = bo.y;
          out[img*POST*4 + rank*4 + 2] = bo.z;
          out[img*POST*4 + rank*4 + 3] = bo.w;
          out[2*POST*4 + img*POST + rank] = sc;
        }
      }
    }
  }
}

extern "C" void kernel_launch(void* const* d_in, const int* in_sizes, int n_in,
                              void* d_out, int out_size, void* d_ws, size_t ws_size,
                              hipStream_t stream){
  (void)in_sizes; (void)n_in; (void)out_size; (void)ws_size;
  const float*  obj     = (const float*)d_in[0];
  const float4* deltas  = (const float4*)d_in[1];
  const float4* anchors = (const float4*)d_in[2];
  float* out = (float*)d_out;
  char* ws = (char*)d_ws;
  void* args[] = { (void*)&obj, (void*)&deltas, (void*)&anchors, (void*)&out, (void*)&ws };
  hipLaunchCooperativeKernel((void*)k_all, dim3(NBLK), dim3(256), args, 0, stream);
}

// Round 12
// 261.476 us; speedup vs baseline: 1.4412x; 1.4412x over previous
//
#include <hip/hip_runtime.h>

typedef unsigned long long u64;
typedef unsigned int u32;

#define R_TOT 159882
#define POST 1000
#define IMG_SZ 800.0f
#define NMS_TH 0.7f
#define BBOX_CLIP 4.135166556742356f
#define LCAP 1024
#define TRI_FULL 7680   // 64 * 120 words: packed lower-triangle (tr=1..15) per level
#define TRI_LDS  6720   // 64 * 105 words: tiles tr<=14 staged in LDS

__device__ __forceinline__ float fadd_(float a, float b){ return __fadd_rn(a,b); }
__device__ __forceinline__ float fsub_(float a, float b){ return __fsub_rn(a,b); }
__device__ __forceinline__ float fmul_(float a, float b){ return __fmul_rn(a,b); }

__device__ __forceinline__ int lvl_len(int l){ const int L[5]={120000,30000,7500,1875,507}; return L[l]; }
__device__ __forceinline__ int lvl_off(int l){ const int L[5]={0,120000,150000,157500,159375}; return L[l]; }
__device__ __forceinline__ int lvl_k(int l){ const int L[5]={1000,1000,1000,1000,507}; return L[l]; }

__device__ __forceinline__ u32 mono_(u32 u){ return (u & 0x80000000u) ? ~u : (u | 0x80000000u); }

__device__ __forceinline__ u64 readlane64(u64 v, int i){
  u32 lo = (u32)__builtin_amdgcn_readlane((int)(u32)v, i);
  u32 hi = (u32)__builtin_amdgcn_readlane((int)(u32)(v >> 32), i);
  return ((u64)hi << 32) | (u64)lo;
}

__device__ __forceinline__ int lbound_(const u64* a, int n, u64 key){
  int lo = 0, hi = n;
  while (lo < hi){ int mid = (lo + hi) >> 1; if (a[mid] < key) lo = mid + 1; else hi = mid; }
  return lo;
}

// ctrs: [0..9]=done2 (collect), [10..19]=done3 (mask), [20..29]=cntg, [30..39]=cnt2

// ---------- K1: per-slice 12-bit histogram (overwrite) + zero counters ----------
__global__ __launch_bounds__(256) void k_hist(const float* __restrict__ obj,
                                              int* hist16, int* ctrs){
  int g = blockIdx.x, sl = blockIdx.y;
  int img = g/5, lvl = g%5;
  int n = lvl_len(lvl), s0 = lvl_off(lvl);
  __shared__ int lh[4096];
  int tid = threadIdx.x;
  if (g == 0 && sl == 0 && tid < 40) ctrs[tid] = 0;   // visible to K2 via kernel boundary
  for (int i = tid; i < 4096; i += 256) lh[i] = 0;
  __syncthreads();
  int lo = (int)((long long)n * sl / 16), hiS = (int)((long long)n * (sl+1) / 16);
  const float* p = obj + img*R_TOT + s0;
  #pragma unroll 4
  for (int e = lo + tid; e < hiS; e += 256){
    u32 mu = mono_(__float_as_uint(p[e]));
    atomicAdd(&lh[(~mu) >> 20], 1);
  }
  __syncthreads();
  int* dst = hist16 + (g*16 + sl)*4096;
  for (int i = tid; i < 4096; i += 256) dst[i] = lh[i];
}

// ---------- K2: redundant pick + slice collect; tail block runs full seldecode ----------
__global__ __launch_bounds__(1024) void k_colsel(const float* __restrict__ obj,
                                                 const float4* __restrict__ deltas,
                                                 const float4* __restrict__ anchors,
                                                 const int* __restrict__ hist16,
                                                 int* ctrs, u64* mainG, u64* LbufG,
                                                 float4* boxL, float* scoreL,
                                                 u64* okeyN, float4* nboxG, int* ncnt){
  int g = blockIdx.x, sl = blockIdx.y;
  int img = g/5, lvl = g%5;
  int s0 = lvl_off(lvl), n = lvl_len(lvl), k = lvl_k(lvl);
  const float* p = obj + img*R_TOT + s0;
  int* done2 = ctrs;
  int* cntg  = ctrs + 20;
  int* cnt2  = ctrs + 30;
  __shared__ u64 mainL[1024];
  __shared__ u64 Lbuf[LCAP];
  __shared__ u64 lokey[1024];
  __shared__ float4 lbox[1024];
  __shared__ u64 validW[16];
  __shared__ int wsum[16];
  __shared__ int h16s[16];
  __shared__ int sh_b, sh_rem0, sh_sc, sh_rem, sh_win;
  __shared__ u64 sh_thr;
  int tid = threadIdx.x, lane = tid & 63, wid = tid >> 6;

  // --- pick (computed redundantly by every block; no inter-block sync needed) ---
  {
    const int* hb = hist16 + g*16*4096;
    int hh[4] = {0,0,0,0};
    #pragma unroll
    for (int s2 = 0; s2 < 16; s2++){
      const int* hs = hb + s2*4096 + 4*tid;
      hh[0] += hs[0]; hh[1] += hs[1]; hh[2] += hs[2]; hh[3] += hs[3];
    }
    int part = hh[0] + hh[1] + hh[2] + hh[3];
    int x = part;
    for (int d = 1; d < 64; d <<= 1){ int y = __shfl_up(x, d); if (lane >= d) x += y; }
    if (lane == 63) wsum[wid] = x;
    __syncthreads();
    int add = 0;
    for (int w = 0; w < wid; w++) add += wsum[w];
    int incl = x + add, excl = incl - part;
    if (excl < k && k <= incl){
      int cum = excl;
      #pragma unroll
      for (int q = 0; q < 4; q++){
        if (cum + hh[q] >= k){ sh_b = 4*tid + q; sh_rem0 = k - cum; break; }
        cum += hh[q];
      }
    }
    __syncthreads();
  }
  int bs = sh_b, rem = sh_rem0;

  // --- collect my slice ---
  {
    int lo = (int)((long long)n * sl / 16), hiS = (int)((long long)n * (sl+1) / 16);
    #pragma unroll 4
    for (int e = lo + tid; e < hiS; e += 1024){
      u32 mu = mono_(__float_as_uint(p[e]));
      u64 key56 = (((u64)(~mu)) << 24) | (u32)(s0 + e);
      int bin = (int)(key56 >> 44);
      if (bin < bs){ int pos = atomicAdd(&cntg[g], 1); mainG[g*1024 + pos] = key56; }
      else if (bin == bs){ int pos = atomicAdd(&cnt2[g], 1); if (pos < LCAP) LbufG[g*LCAP + pos] = key56; }
    }
  }
  __syncthreads();
  __threadfence();                       // release my slice's writes (device scope)
  if (tid == 0) sh_win = (atomicAdd(&done2[g], 1) == 15) ? 1 : 0;
  __syncthreads();
  if (!sh_win) return;
  __threadfence();                       // acquire the other 15 blocks' writes

  // --- seldecode (R9's proven 1024-thread body) ---
  int nb = cntg[g], c2 = cnt2[g];
  mainL[tid] = (tid < nb) ? mainG[g*1024 + tid] : ~0ull;
  if (tid == 0){ sh_sc = 0; sh_rem = rem; }
  int c2c = c2 < LCAP ? c2 : LCAP;
  if (tid < c2c) Lbuf[tid] = LbufG[g*LCAP + tid];
  __syncthreads();
  if (c2 <= LCAP){
    if (tid < c2){
      u64 kk = Lbuf[tid];
      int rk = 0;
      for (int q = 0; q < c2; q++) rk += (Lbuf[q] < kk) ? 1 : 0;
      if (rk < rem){ int p2 = atomicAdd(&sh_sc, 1); mainL[nb + p2] = kk; }
    }
  } else {
    // fallback: 4-bit radix refine over global (never hit on bench data)
    if (tid == 0) sh_thr = ((u64)bs) << 44;
    __syncthreads();
    for (int shift = 40; shift >= 0; shift -= 4){
      if (tid < 16) h16s[tid] = 0;
      __syncthreads();
      u64 pref = sh_thr;
      u64 himask = ~((1ull << (shift+4)) - 1ull);
      for (int e = tid; e < n; e += 1024){
        u32 mu = mono_(__float_as_uint(p[e]));
        u64 kk = (((u64)(~mu)) << 24) | (u32)(s0 + e);
        if ((kk & himask) == (pref & himask)) atomicAdd(&h16s[(int)((kk >> shift) & 15)], 1);
      }
      __syncthreads();
      if (tid == 0){
        int r2 = sh_rem, cum = 0;
        for (int d = 0; d < 16; d++){
          int hb2 = h16s[d];
          if (cum + hb2 >= r2){ sh_thr = pref | ((u64)d << shift); sh_rem = r2 - cum; break; }
          cum += hb2;
        }
      }
      __syncthreads();
    }
    u64 thr = sh_thr;
    for (int e = tid; e < n; e += 1024){
      u32 mu = mono_(__float_as_uint(p[e]));
      u64 kk = (((u64)(~mu)) << 24) | (u32)(s0 + e);
      if ((int)(kk >> 44) == bs && kk <= thr){ int p2 = atomicAdd(&sh_sc, 1); mainL[nb + p2] = kk; }
    }
  }
  __syncthreads();
  // bitonic sort 1024
  for (int k2 = 2; k2 <= 1024; k2 <<= 1){
    for (int j = k2 >> 1; j > 0; j >>= 1){
      __syncthreads();
      int i = tid, ixj = i ^ j;
      if (ixj > i){
        u64 a = mainL[i], b = mainL[ixj];
        bool up = (i & k2) == 0;
        if ((a > b) == up){ mainL[i] = b; mainL[ixj] = a; }
      }
    }
  }
  __syncthreads();
  // decode + clip + valid + sigmoid + okey
  int r = tid;
  bool validF = false;
  if (r < k){
    int idx = (int)(mainL[r] & 0xFFFFFFu);
    float4 a = anchors[idx];
    float4 d = deltas[img*R_TOT + idx];
    float o = obj[img*R_TOT + idx];
    float wa = fsub_(a.z, a.x), ha = fsub_(a.w, a.y);
    float cxa = fadd_(a.x, fmul_(0.5f, wa)), cya = fadd_(a.y, fmul_(0.5f, ha));
    float dw = fminf(d.z, BBOX_CLIP), dh = fminf(d.w, BBOX_CLIP);
    float cx = fadd_(fmul_(d.x, wa), cxa), cy = fadd_(fmul_(d.y, ha), cya);
    float w  = fmul_(expf(dw), wa),        h  = fmul_(expf(dh), ha);
    float x1 = fsub_(cx, fmul_(0.5f, w)), y1 = fsub_(cy, fmul_(0.5f, h));
    float x2 = fadd_(cx, fmul_(0.5f, w)), y2 = fadd_(cy, fmul_(0.5f, h));
    x1 = fminf(fmaxf(x1, 0.0f), IMG_SZ); y1 = fminf(fmaxf(y1, 0.0f), IMG_SZ);
    x2 = fminf(fmaxf(x2, 0.0f), IMG_SZ); y2 = fminf(fmaxf(y2, 0.0f), IMG_SZ);
    validF = (fsub_(x2, x1) >= 1e-3f) && (fsub_(y2, y1) >= 1e-3f);
    float e = expf(-o);
    float sig = __fdiv_rn(1.0f, fadd_(1.0f, e));
    float s = validF ? sig : -1.0f;
    u32 sb = __float_as_uint(s);
    u32 ms = (sb & 0x80000000u) ? ~sb : (sb | 0x80000000u);
    float4 b4 = make_float4(x1, y1, x2, y2);
    boxL[g*1024 + r] = b4;
    scoreL[g*1024 + r] = sig;
    lokey[r] = (((u64)(~ms)) << 32) | (u32)(lvl*1000 + r);
    lbox[r] = b4;
  }
  validW[wid] = __ballot(validF);
  __syncthreads();
  // valid-compaction (wave 0): nboxG (+801*lvl) and okeyN in compacted order
  if (tid < 64){
    int cnt = 0;
    float off = (float)lvl * 801.0f;
    #pragma unroll
    for (int w = 0; w < 16; w++){
      u64 mask = validW[w];
      int r2 = w*64 + tid;
      bool v = (mask >> tid) & 1ull;
      int before = __popcll(mask & ((1ull << tid) - 1ull));
      if (v){
        int pos = cnt + before;
        float4 b = lbox[r2];
        nboxG[g*1024 + pos] = make_float4(fadd_(b.x,off), fadd_(b.y,off), fadd_(b.z,off), fadd_(b.w,off));
        okeyN[g*1024 + pos] = lokey[r2];
      }
      cnt += __popcll(mask);
    }
    if (tid == 0) ncnt[g] = cnt;
  }
}

// ---------- K3: IoU mask tiles (4 tiles/block, one per wave); tail block runs scan ----------
__global__ __launch_bounds__(256) void k_maskscan(const float4* __restrict__ nboxG,
                                                  const int* __restrict__ ncnt,
                                                  int* ctrs, u64* LTG, u64* diagF, u64* keptW){
  __shared__ u64 SH[7744];      // mask phase: shb (4 waves x 64 float4); scan: LT + dFL
  __shared__ u64 KwS[16];
  __shared__ int sh_win;
  int g = blockIdx.x, tid = threadIdx.x, lane = tid & 63, wid = tid >> 6;
  int* done3 = ctrs + 10;
  int m = ncnt[g];
  // --- mask: this wave's tile ---
  int tbase = blockIdx.y*4 + wid;     // 0..135
  {
    int tr = 0;
    while (((tr+1)*(tr+2))/2 <= tbase) tr++;
    int tw = tbase - (tr*(tr+1))/2;
    if (tr*64 < m){
      float4* shb = (float4*)SH;      // per-wave slot: shb[wid*64 + lane]
      if (tw*64 + lane < m) shb[wid*64 + lane] = nboxG[g*1024 + tw*64 + lane];
      // intra-wave LDS produce->consume: compiler-inserted lgkmcnt, no barrier needed
      int j = tr*64 + lane;
      float4 a = (j < m) ? nboxG[g*1024 + j] : make_float4(0,0,0,0);
      float areaA = fmul_(fsub_(a.z,a.x), fsub_(a.w,a.y));
      int imax = m - tw*64; if (imax > 64) imax = 64;
      if (tw == tr){
        u64 bitsF = 0;
        for (int ii = lane+1; ii < imax; ii++){
          float4 b = shb[wid*64 + ii];
          float ltx = fmaxf(a.x, b.x), lty = fmaxf(a.y, b.y);
          float rbx = fminf(a.z, b.z), rby = fminf(a.w, b.w);
          float wx = fmaxf(fsub_(rbx, ltx), 0.0f), wy = fmaxf(fsub_(rby, lty), 0.0f);
          float inter = fmul_(wx, wy);
          float areaB = fmul_(fsub_(b.z,b.x), fsub_(b.w,b.y));
          float den = fadd_(fsub_(fadd_(areaA, areaB), inter), 1e-9f);
          if (__fdiv_rn(inter, den) > NMS_TH) bitsF |= (1ull << ii);
        }
        if (j < m) diagF[g*1024 + j] = bitsF;
      } else {
        u64 bits = 0;
        #pragma unroll 4
        for (int ii = 0; ii < imax; ii++){
          float4 b = shb[wid*64 + ii];
          float ltx = fmaxf(a.x, b.x), lty = fmaxf(a.y, b.y);
          float rbx = fminf(a.z, b.z), rby = fminf(a.w, b.w);
          float wx = fmaxf(fsub_(rbx, ltx), 0.0f), wy = fmaxf(fsub_(rby, lty), 0.0f);
          float inter = fmul_(wx, wy);
          float areaB = fmul_(fsub_(b.z,b.x), fsub_(b.w,b.y));
          float den = fadd_(fsub_(fadd_(areaA, areaB), inter), 1e-9f);
          if (__fdiv_rn(inter, den) > NMS_TH) bits |= (1ull << ii);
        }
        if (j < m) LTG[(size_t)g*TRI_FULL + ((tr*(tr-1))/2 + tw)*64 + lane] = bits;
      }
    }
  }
  __syncthreads();
  __threadfence();
  if (tid == 0) sh_win = (atomicAdd(&done3[g], 1) == 33) ? 1 : 0;
  __syncthreads();
  if (!sh_win) return;
  __threadfence();
  // --- scan (R9's proven body): stage triangle + diagF, scalar ffs chain ---
  u64* LT = SH;
  u64* dFL = SH + TRI_LDS;
  for (int i = tid; i < TRI_LDS; i += 256) LT[i] = LTG[(size_t)g*TRI_FULL + i];
  for (int i = tid; i < 1024; i += 256) dFL[i] = diagF[g*1024 + i];
  if (tid < 16) KwS[tid] = 0;
  __syncthreads();
  if (tid < 64){
    int nch = (m + 63) >> 6;
    for (int c = 0; c < nch; c++){
      int row = c*64 + lane;
      bool inr = row < m;
      u64 supp = 0;
      if (c < 15){
        int tb = (c*(c-1))/2;
        for (int q = 0; q < c; q++) supp |= LT[(tb+q)*64 + lane] & KwS[q];
      } else {
        const u64* gp = LTG + (size_t)g*TRI_FULL + 105*64;
        #pragma unroll
        for (int q = 0; q < 15; q++) supp |= gp[q*64 + lane] & KwS[q];
      }
      u64 fwd = inr ? dFL[row] : 0;
      u64 live = __ballot(inr && (supp == 0));
      u64 fz = __ballot(fwd != 0);
      u64 kept = 0;
      while (live){
        if (!(live & fz)){ kept |= live; break; }
        int i = __builtin_ctzll(live);
        kept |= (1ull << i);
        live &= ~(1ull << i);
        live &= ~readlane64(fwd, i);
      }
      KwS[c] = kept;
      if (lane == 0) keptW[g*16 + c] = kept;
    }
  }
}

// ---------- K4: merge (verbatim R9) ----------
__global__ __launch_bounds__(1024) void k_merge(const u64* __restrict__ keptW,
                                                const u64* __restrict__ okeyN,
                                                const int* __restrict__ ncnt,
                                                const float4* __restrict__ boxL,
                                                const float* __restrict__ scoreL,
                                                float* out){
  int img = blockIdx.x, tid = threadIdx.x, lane = tid & 63, wid = tid >> 6;
  __shared__ u64 runs[5*1024];
  __shared__ int cl[5];
  if (tid < 5) cl[tid] = 0;
  __syncthreads();
  if (wid < 5){
    int l = wid, g = img*5 + l;
    int m = ncnt[g];
    int nch = (m + 63) >> 6;
    int cnt = 0;
    for (int c = 0; c < nch; c++){
      u64 w = keptW[g*16 + c];
      bool kp = (w >> lane) & 1ull;
      int before = __popcll(w & ((1ull << lane) - 1ull));
      if (kp) runs[l*1024 + cnt + before] = okeyN[g*1024 + c*64 + lane];
      cnt += __popcll(w);
    }
    if (lane == 0) cl[l] = cnt;
  }
  __syncthreads();
  for (int t = tid; t < POST; t += 1024){
    out[img*POST*4 + t*4 + 0] = 0.0f;
    out[img*POST*4 + t*4 + 1] = 0.0f;
    out[img*POST*4 + t*4 + 2] = 0.0f;
    out[img*POST*4 + t*4 + 3] = 0.0f;
    out[2*POST*4 + img*POST + t] = -1.0f;
  }
  __syncthreads();
  for (int idx = tid; idx < 5*1024; idx += 1024){
    int l = idx >> 10, i = idx & 1023;
    if (i < cl[l]){
      u64 key = runs[l*1024 + i];
      int rank = i;
      #pragma unroll
      for (int l2 = 0; l2 < 5; l2++)
        if (l2 != l) rank += lbound_(runs + l2*1024, cl[l2], key);
      if (rank < POST){
        int pos = (int)(key & 0xFFFFFFFFull);
        int lvl = pos / 1000, r = pos - lvl*1000;
        int gg = img*5 + lvl;
        float4 bo = boxL[gg*1024 + r];
        float sc = scoreL[gg*1024 + r];
        out[img*POST*4 + rank*4 + 0] = bo.x;
        out[img*POST*4 + rank*4 + 1] = bo.y;
        out[img*POST*4 + rank*4 + 2] = bo.z;
        out[img*POST*4 + rank*4 + 3] = bo.w;
        out[2*POST*4 + img*POST + rank] = sc;
      }
    }
  }
}

extern "C" void kernel_launch(void* const* d_in, const int* in_sizes, int n_in,
                              void* d_out, int out_size, void* d_ws, size_t ws_size,
                              hipStream_t stream){
  (void)in_sizes; (void)n_in; (void)out_size; (void)ws_size;
  const float*  obj     = (const float*)d_in[0];
  const float4* deltas  = (const float4*)d_in[1];
  const float4* anchors = (const float4*)d_in[2];
  float* out = (float*)d_out;
  char* ws = (char*)d_ws;
  int* hist16  = (int*)(ws + 0);           // 10*16*4096 int -> 2621440
  int* ctrs    = (int*)(ws + 2621440);     // 40 int         -> 2621696
  u64* mainG   = (u64*)(ws + 2621696);     // 10*1024 u64    -> 2703616
  u64* LbufG   = (u64*)(ws + 2703616);     // 10*1024 u64    -> 2785536
  float4* boxL = (float4*)(ws + 2785536);  // 10*1024 f4     -> 2949376
  float* scoreL= (float*)(ws + 2949376);   // 10*1024 f32    -> 2990336
  u64* okeyN   = (u64*)(ws + 2990336);     // 10*1024 u64    -> 3072256
  float4* nboxG= (float4*)(ws + 3072256);  // 10*1024 f4     -> 3236096
  u64* LTG     = (u64*)(ws + 3236096);     // 10*7680 u64    -> 3850496
  u64* diagF   = (u64*)(ws + 3850496);     // 10*1024 u64    -> 3932416
  u64* keptW   = (u64*)(ws + 3932416);     // 10*16 u64      -> 3933696
  int* ncnt    = (int*)(ws + 3933696);     // 10 int

  {
    dim3 gh(10, 16);
    k_hist<<<gh, 256, 0, stream>>>(obj, hist16, ctrs);
  }
  {
    dim3 gc(10, 16);
    k_colsel<<<gc, 1024, 0, stream>>>(obj, deltas, anchors, hist16, ctrs, mainG, LbufG,
                                      boxL, scoreL, okeyN, nboxG, ncnt);
  }
  {
    dim3 gm(10, 34);
    k_maskscan<<<gm, 256, 0, stream>>>(nboxG, ncnt, ctrs, LTG, diagF, keptW);
  }
  k_merge<<<2, 1024, 0, stream>>>(keptW, okeyN, ncnt, boxL, scoreL, out);
}

// Round 13
// 206.920 us; speedup vs baseline: 1.8212x; 1.2637x over previous
//
#include <hip/hip_runtime.h>

typedef unsigned long long u64;
typedef unsigned int u32;

#define R_TOT 159882
#define POST 1000
#define IMG_SZ 800.0f
#define NMS_TH 0.7f
#define BBOX_CLIP 4.135166556742356f
#define LCAP 1024
#define TRI_FULL 7680   // 64 * 120 words: packed lower-triangle (tr=1..15) per level
#define TRI_LDS  6720   // 64 * 105 words: tiles tr<=14 staged in LDS

__device__ __forceinline__ float fadd_(float a, float b){ return __fadd_rn(a,b); }
__device__ __forceinline__ float fsub_(float a, float b){ return __fsub_rn(a,b); }
__device__ __forceinline__ float fmul_(float a, float b){ return __fmul_rn(a,b); }

__device__ __forceinline__ int lvl_len(int l){ const int L[5]={120000,30000,7500,1875,507}; return L[l]; }
__device__ __forceinline__ int lvl_off(int l){ const int L[5]={0,120000,150000,157500,159375}; return L[l]; }
__device__ __forceinline__ int lvl_k(int l){ const int L[5]={1000,1000,1000,1000,507}; return L[l]; }

__device__ __forceinline__ u32 mono_(u32 u){ return (u & 0x80000000u) ? ~u : (u | 0x80000000u); }

__device__ __forceinline__ u64 readlane64(u64 v, int i){
  u32 lo = (u32)__builtin_amdgcn_readlane((int)(u32)v, i);
  u32 hi = (u32)__builtin_amdgcn_readlane((int)(u32)(v >> 32), i);
  return ((u64)hi << 32) | (u64)lo;
}

// ---------- 1. per-slice 12-bit histogram: LDS-private, full overwrite (no memset) ----------
__global__ __launch_bounds__(256) void k_hist(const float* __restrict__ obj, int* hist16){
  int g = blockIdx.x, sl = blockIdx.y;
  int img = g/5, lvl = g%5;
  int n = lvl_len(lvl), s0 = lvl_off(lvl);
  __shared__ int lh[4096];
  int tid = threadIdx.x;
  for (int i = tid; i < 4096; i += 256) lh[i] = 0;
  __syncthreads();
  int lo = (int)((long long)n * sl / 16), hiS = (int)((long long)n * (sl+1) / 16);
  const float* p = obj + img*R_TOT + s0;
  #pragma unroll 4
  for (int e = lo + tid; e < hiS; e += 256){
    u32 mu = mono_(__float_as_uint(p[e]));
    atomicAdd(&lh[(~mu) >> 20], 1);
  }
  __syncthreads();
  int* dst = hist16 + (g*16 + sl)*4096;
  for (int i = tid; i < 4096; i += 256) dst[i] = lh[i];
}

// ---------- 2. sum slices + pick the k-th bin; zero the collect counters ----------
__global__ __launch_bounds__(1024) void k_pick(const int* __restrict__ hist16,
                                               int* bstarG, int* remG, int* cntg, int* cnt2){
  int g = blockIdx.x, lvl = g % 5, k = lvl_k(lvl);
  int tid = threadIdx.x, lane = tid & 63, wid = tid >> 6;
  __shared__ int wsum[16];
  const int* hb = hist16 + g*16*4096;
  int hh[4] = {0,0,0,0};
  #pragma unroll
  for (int sl = 0; sl < 16; sl++){
    const int* hs = hb + sl*4096 + 4*tid;
    hh[0] += hs[0]; hh[1] += hs[1]; hh[2] += hs[2]; hh[3] += hs[3];
  }
  int part = hh[0] + hh[1] + hh[2] + hh[3];
  int x = part;
  for (int d = 1; d < 64; d <<= 1){ int y = __shfl_up(x, d); if (lane >= d) x += y; }
  if (lane == 63) wsum[wid] = x;
  __syncthreads();
  int add = 0;
  for (int w = 0; w < wid; w++) add += wsum[w];
  int incl = x + add, excl = incl - part;
  if (excl < k && k <= incl){
    int cum = excl;
    #pragma unroll
    for (int q = 0; q < 4; q++){
      if (cum + hh[q] >= k){ bstarG[g] = 4*tid + q; remG[g] = k - cum; break; }
      cum += hh[q];
    }
  }
  if (tid == 0){ cntg[g] = 0; cnt2[g] = 0; }
}

// ---------- 3. wide collect scan: bin<b* -> mainG, bin==b* -> LbufG ----------
__global__ __launch_bounds__(256) void k_collect(const float* __restrict__ obj,
                                                 const int* __restrict__ bstarG,
                                                 int* cntg, int* cnt2,
                                                 u64* mainG, u64* LbufG){
  int g = blockIdx.x, sl = blockIdx.y;
  int img = g/5, lvl = g%5;
  int n = lvl_len(lvl), s0 = lvl_off(lvl);
  int lo = (int)((long long)n * sl / 16), hiS = (int)((long long)n * (sl+1) / 16);
  const float* p = obj + img*R_TOT + s0;
  int bs = bstarG[g];
  #pragma unroll 8
  for (int e = lo + threadIdx.x; e < hiS; e += 256){
    u32 mu = mono_(__float_as_uint(p[e]));
    u64 key56 = (((u64)(~mu)) << 24) | (u32)(s0 + e);
    int bin = (int)(key56 >> 44);
    if (bin < bs){ int pos = atomicAdd(&cntg[g], 1); mainG[g*1024 + pos] = key56; }
    else if (bin == bs){ int pos = atomicAdd(&cnt2[g], 1); if (pos < LCAP) LbufG[g*LCAP + pos] = key56; }
  }
}

// ---------- 4. tie-resolve + sort + decode + prep (okey written in compacted order) ----------
__global__ __launch_bounds__(1024) void k_seldecode(const float* __restrict__ obj,
                                                    const float4* __restrict__ deltas,
                                                    const float4* __restrict__ anchors,
                                                    const u64* __restrict__ mainG,
                                                    const u64* __restrict__ LbufG,
                                                    const int* __restrict__ cntg,
                                                    const int* __restrict__ cnt2,
                                                    const int* __restrict__ remG,
                                                    const int* __restrict__ bstarG,
                                                    float4* boxL, float* scoreL,
                                                    float4* nbox, u64* okeyN, int* ncnt){
  int g = blockIdx.x, img = g/5, lvl = g%5;
  int s0 = lvl_off(lvl), n = lvl_len(lvl), k = lvl_k(lvl);
  const float* p = obj + img*R_TOT + s0;
  __shared__ u64 Lbuf[LCAP];
  __shared__ u64 mainL[1024];
  __shared__ float4 lbox[1024];
  __shared__ u64 lokey[1024];
  __shared__ unsigned char lval[1024];
  __shared__ int h16[16];
  __shared__ int sh_sc, sh_rem;
  __shared__ u64 sh_thr;
  int tid = threadIdx.x, lane = tid & 63;
  int nb = cntg[g];
  int c2 = cnt2[g];
  int rem = remG[g];
  int bs = bstarG[g];
  mainL[tid] = (tid < nb) ? mainG[g*1024 + tid] : ~0ull;
  if (tid == 0){ sh_sc = 0; sh_rem = rem; }
  int c2c = c2 < LCAP ? c2 : LCAP;
  for (int e = tid; e < c2c; e += 1024) Lbuf[e] = LbufG[g*LCAP + e];
  __syncthreads();
  if (c2 <= LCAP){
    for (int e = tid; e < c2; e += 1024){
      u64 kk = Lbuf[e];
      int rk = 0;
      for (int q = 0; q < c2; q++) rk += (Lbuf[q] < kk) ? 1 : 0;
      if (rk < rem){ int p2 = atomicAdd(&sh_sc, 1); mainL[nb + p2] = kk; }
    }
  } else {
    // fallback: 4-bit radix refine over global (never hit on bench data)
    if (tid == 0) sh_thr = ((u64)bs) << 44;
    __syncthreads();
    for (int shift = 40; shift >= 0; shift -= 4){
      if (tid < 16) h16[tid] = 0;
      __syncthreads();
      u64 pref = sh_thr;
      u64 himask = ~((1ull << (shift+4)) - 1ull);
      for (int e = tid; e < n; e += 1024){
        u32 mu = mono_(__float_as_uint(p[e]));
        u64 kk = (((u64)(~mu)) << 24) | (u32)(s0 + e);
        if ((kk & himask) == (pref & himask)) atomicAdd(&h16[(int)((kk >> shift) & 15)], 1);
      }
      __syncthreads();
      if (tid == 0){
        int r2 = sh_rem, cum = 0;
        for (int d = 0; d < 16; d++){
          int hb = h16[d];
          if (cum + hb >= r2){ sh_thr = pref | ((u64)d << shift); sh_rem = r2 - cum; break; }
          cum += hb;
        }
      }
      __syncthreads();
    }
    u64 thr = sh_thr;
    for (int e = tid; e < n; e += 1024){
      u32 mu = mono_(__float_as_uint(p[e]));
      u64 kk = (((u64)(~mu)) << 24) | (u32)(s0 + e);
      if ((int)(kk >> 44) == bs && kk <= thr){ int p2 = atomicAdd(&sh_sc, 1); mainL[nb + p2] = kk; }
    }
  }
  __syncthreads();
  // --- bitonic sort 1024 ---
  for (int k2 = 2; k2 <= 1024; k2 <<= 1){
    for (int j = k2 >> 1; j > 0; j >>= 1){
      __syncthreads();
      int i = tid, ixj = i ^ j;
      if (ixj > i){
        u64 a = mainL[i], b = mainL[ixj];
        bool up = (i & k2) == 0;
        if ((a > b) == up){ mainL[i] = b; mainL[ixj] = a; }
      }
    }
  }
  __syncthreads();
  // --- decode + clip + valid + sigmoid + okey ---
  int r = tid, t = g*1024 + r;
  if (r < k){
    int idx = (int)(mainL[r] & 0xFFFFFFu);
    float4 a = anchors[idx];
    float4 d = deltas[img*R_TOT + idx];
    float o = obj[img*R_TOT + idx];
    float wa = fsub_(a.z, a.x), ha = fsub_(a.w, a.y);
    float cxa = fadd_(a.x, fmul_(0.5f, wa)), cya = fadd_(a.y, fmul_(0.5f, ha));
    float dw = fminf(d.z, BBOX_CLIP), dh = fminf(d.w, BBOX_CLIP);
    float cx = fadd_(fmul_(d.x, wa), cxa), cy = fadd_(fmul_(d.y, ha), cya);
    float w  = fmul_(expf(dw), wa),        h  = fmul_(expf(dh), ha);
    float x1 = fsub_(cx, fmul_(0.5f, w)), y1 = fsub_(cy, fmul_(0.5f, h));
    float x2 = fadd_(cx, fmul_(0.5f, w)), y2 = fadd_(cy, fmul_(0.5f, h));
    x1 = fminf(fmaxf(x1, 0.0f), IMG_SZ); y1 = fminf(fmaxf(y1, 0.0f), IMG_SZ);
    x2 = fminf(fmaxf(x2, 0.0f), IMG_SZ); y2 = fminf(fmaxf(y2, 0.0f), IMG_SZ);
    bool valid = (fsub_(x2, x1) >= 1e-3f) && (fsub_(y2, y1) >= 1e-3f);
    float e = expf(-o);
    float sig = __fdiv_rn(1.0f, fadd_(1.0f, e));
    float s = valid ? sig : -1.0f;
    u32 sb = __float_as_uint(s);
    u32 ms = (sb & 0x80000000u) ? ~sb : (sb | 0x80000000u);
    float4 b4 = make_float4(x1, y1, x2, y2);
    boxL[t] = b4;
    scoreL[t] = sig;
    lokey[r] = (((u64)(~ms)) << 32) | (u32)(lvl*1000 + r);
    lbox[r] = b4;
    lval[r] = valid ? 1 : 0;
  } else {
    lval[r] = 0;
  }
  __syncthreads();
  // --- valid-compaction (wave 0): nbox (+801*lvl offset) and okey in compacted order ---
  if (tid < 64){
    int cnt = 0;
    float off = (float)lvl * 801.0f;
    for (int base = 0; base < k; base += 64){
      int r2 = base + lane;
      bool v = (r2 < k) && lval[r2];
      float4 b = lbox[r2 < k ? r2 : 0];
      u64 mask = __ballot(v);
      int before = __popcll(mask & ((1ull << lane) - 1ull));
      if (v){
        int pos = cnt + before;
        nbox[g*1024 + pos] = make_float4(fadd_(b.x,off), fadd_(b.y,off), fadd_(b.z,off), fadd_(b.w,off));
        okeyN[g*1024 + pos] = lokey[r2];
      }
      cnt += __popcll(mask);
    }
    if (lane == 0) ncnt[g] = cnt;
  }
}

// ---------- 5. IoU bitmask: packed column-major triangle + forward diagonal words ----------
__global__ __launch_bounds__(64) void k_mask(const float4* __restrict__ nbox,
                                             const int* __restrict__ ncnt,
                                             u64* LTG, u64* diagF){
  int g = blockIdx.x, tr = blockIdx.y, tw = blockIdx.z;
  if (tw > tr) return;
  int m = ncnt[g];
  if (tr*64 >= m) return;
  __shared__ float4 shb[64];
  int lane = threadIdx.x;
  if (tw*64 + lane < m) shb[lane] = nbox[g*1024 + tw*64 + lane];
  __syncthreads();
  int j = tr*64 + lane;
  if (j >= m) return;
  float4 a = nbox[g*1024 + j];
  float areaA = fmul_(fsub_(a.z,a.x), fsub_(a.w,a.y));
  int imax = m - tw*64; if (imax > 64) imax = 64;
  if (tw == tr){
    // diagonal: only forward word (whom lane suppresses, ii > lane)
    u64 bitsF = 0;
    for (int ii = lane+1; ii < imax; ii++){
      float4 b = shb[ii];
      float ltx = fmaxf(a.x, b.x), lty = fmaxf(a.y, b.y);
      float rbx = fminf(a.z, b.z), rby = fminf(a.w, b.w);
      float wx = fmaxf(fsub_(rbx, ltx), 0.0f), wy = fmaxf(fsub_(rby, lty), 0.0f);
      float inter = fmul_(wx, wy);
      float areaB = fmul_(fsub_(b.z,b.x), fsub_(b.w,b.y));
      float den = fadd_(fsub_(fadd_(areaA, areaB), inter), 1e-9f);
      if (__fdiv_rn(inter, den) > NMS_TH) bitsF |= (1ull << ii);
    }
    diagF[g*1024 + j] = bitsF;
  } else {
    u64 bits = 0;
    for (int ii = 0; ii < imax; ii++){
      float4 b = shb[ii];
      float ltx = fmaxf(a.x, b.x), lty = fmaxf(a.y, b.y);
      float rbx = fminf(a.z, b.z), rby = fminf(a.w, b.w);
      float wx = fmaxf(fsub_(rbx, ltx), 0.0f), wy = fmaxf(fsub_(rby, lty), 0.0f);
      float inter = fmul_(wx, wy);
      float areaB = fmul_(fsub_(b.z,b.x), fsub_(b.w,b.y));
      float den = fadd_(fsub_(fadd_(areaA, areaB), inter), 1e-9f);
      if (__fdiv_rn(inter, den) > NMS_TH) bits |= (1ull << ii);
    }
    // packed column-major: word tw of row (tr*64+lane) at [tri(tr) + tw*64 + lane]
    LTG[(size_t)g*TRI_FULL + ((tr*(tr-1))/2 + tw)*64 + lane] = bits;
  }
}

// ---------- 6. greedy scan from LDS-staged triangle; bulk fast-path chain ----------
__global__ __launch_bounds__(256) void k_scan(const u64* __restrict__ LTG,
                                              const u64* __restrict__ diagF,
                                              const int* __restrict__ ncnt,
                                              u64* keptW){
  __shared__ u64 LT[TRI_LDS];
  __shared__ u64 dFL[1024];
  __shared__ u64 KwS[16];
  int g = blockIdx.x, tid = threadIdx.x;
  int m = ncnt[g];
  for (int i = tid; i < TRI_LDS; i += 256) LT[i] = LTG[(size_t)g*TRI_FULL + i];
  for (int i = tid; i < 1024; i += 256) dFL[i] = diagF[g*1024 + i];
  if (tid < 16) KwS[tid] = 0;
  __syncthreads();
  if (tid >= 64) return;
  int lane = tid;
  int nch = (m + 63) >> 6;
  for (int c = 0; c < nch; c++){
    int row = c*64 + lane;
    bool inr = row < m;
    u64 supp = 0;
    if (c < 15){
      int tb = (c*(c-1))/2;
      for (int q = 0; q < c; q++) supp |= LT[(tb+q)*64 + lane] & KwS[q];
    } else {
      const u64* gp = LTG + (size_t)g*TRI_FULL + 105*64;
      #pragma unroll
      for (int q = 0; q < 15; q++) supp |= gp[q*64 + lane] & KwS[q];
    }
    u64 fwd = inr ? dFL[row] : 0;
    u64 live = __ballot(inr && (supp == 0));
    u64 fz = __ballot(fwd != 0);
    u64 kept = 0;
    while (live){
      if (!(live & fz)){ kept |= live; break; }   // no remaining live lane suppresses anyone
      int i = __builtin_ctzll(live);
      kept |= (1ull << i);
      live &= ~(1ull << i);
      live &= ~readlane64(fwd, i);
    }
    KwS[c] = kept;                // uniform value; in-wave DS ordering suffices
    if (lane == 0) keptW[g*16 + c] = kept;
  }
}

__device__ __forceinline__ int lbound(const u64* a, int n, u64 key){
  int lo = 0, hi = n;
  while (lo < hi){ int mid = (lo + hi) >> 1; if (a[mid] < key) lo = mid + 1; else hi = mid; }
  return lo;
}

// ---------- 7. merge: runs from keptW/okeyN, rank by binary search, scatter ----------
__global__ __launch_bounds__(1024) void k_merge(const u64* __restrict__ keptW,
                                                const u64* __restrict__ okeyN,
                                                const int* __restrict__ ncnt,
                                                const float4* __restrict__ boxL,
                                                const float* __restrict__ scoreL,
                                                float* out){
  int img = blockIdx.x, tid = threadIdx.x, lane = tid & 63, wid = tid >> 6;
  __shared__ u64 runs[5*1024];
  __shared__ int cl[5];
  if (tid < 5) cl[tid] = 0;
  __syncthreads();
  if (wid < 5){
    int l = wid, g = img*5 + l;
    int m = ncnt[g];
    int nch = (m + 63) >> 6;
    int cnt = 0;
    for (int c = 0; c < nch; c++){
      u64 w = keptW[g*16 + c];
      bool kp = (w >> lane) & 1ull;
      int before = __popcll(w & ((1ull << lane) - 1ull));
      if (kp) runs[l*1024 + cnt + before] = okeyN[g*1024 + c*64 + lane];
      cnt += __popcll(w);
    }
    if (lane == 0) cl[l] = cnt;
  }
  __syncthreads();
  for (int t = tid; t < POST; t += 1024){
    out[img*POST*4 + t*4 + 0] = 0.0f;
    out[img*POST*4 + t*4 + 1] = 0.0f;
    out[img*POST*4 + t*4 + 2] = 0.0f;
    out[img*POST*4 + t*4 + 3] = 0.0f;
    out[2*POST*4 + img*POST + t] = -1.0f;
  }
  __syncthreads();
  for (int idx = tid; idx < 5*1024; idx += 1024){
    int l = idx >> 10, i = idx & 1023;
    if (i < cl[l]){
      u64 key = runs[l*1024 + i];
      int rank = i;
      #pragma unroll
      for (int l2 = 0; l2 < 5; l2++)
        if (l2 != l) rank += lbound(runs + l2*1024, cl[l2], key);
      if (rank < POST){
        int pos = (int)(key & 0xFFFFFFFFull);
        int lvl = pos / 1000, r = pos - lvl*1000;
        int gg = img*5 + lvl;
        float4 bo = boxL[gg*1024 + r];
        float sc = scoreL[gg*1024 + r];
        out[img*POST*4 + rank*4 + 0] = bo.x;
        out[img*POST*4 + rank*4 + 1] = bo.y;
        out[img*POST*4 + rank*4 + 2] = bo.z;
        out[img*POST*4 + rank*4 + 3] = bo.w;
        out[2*POST*4 + img*POST + rank] = sc;
      }
    }
  }
}

extern "C" void kernel_launch(void* const* d_in, const int* in_sizes, int n_in,
                              void* d_out, int out_size, void* d_ws, size_t ws_size,
                              hipStream_t stream){
  (void)in_sizes; (void)n_in; (void)out_size; (void)ws_size;
  const float*  obj     = (const float*)d_in[0];
  const float4* deltas  = (const float4*)d_in[1];
  const float4* anchors = (const float4*)d_in[2];
  float* out = (float*)d_out;
  char* ws = (char*)d_ws;
  int* hist16  = (int*)(ws + 0);           // 10*16*4096 int -> 2621440
  int* bstarG  = (int*)(ws + 2621440);     //                -> 2621696
  int* remG    = (int*)(ws + 2621696);     //                -> 2621952
  int* cntg    = (int*)(ws + 2621952);     //                -> 2622208
  int* cnt2    = (int*)(ws + 2622208);     //                -> 2622464
  u64* mainG   = (u64*)(ws + 2622464);     // 10*1024 u64    -> 2704384
  u64* LbufG   = (u64*)(ws + 2704384);     // 10*1024 u64    -> 2786304
  float4* boxL = (float4*)(ws + 2786304);  // 10*1024 f4     -> 2950144
  float* scoreL= (float*)(ws + 2950144);   // 10*1024 f32    -> 2991104
  u64* okeyN   = (u64*)(ws + 2991104);     // 10*1024 u64    -> 3073024
  float4* nbox = (float4*)(ws + 3073024);  // 10*1024 f4     -> 3236864
  u64* LTG     = (u64*)(ws + 3236864);     // 10*7680 u64    -> 3851264
  u64* diagF   = (u64*)(ws + 3851264);     // 10*1024 u64    -> 3933184
  u64* keptW   = (u64*)(ws + 3933184);     // 10*16 u64      -> 3934464
  int* ncnt    = (int*)(ws + 3934464);     // 10 int

  {
    dim3 gh(10, 16);
    k_hist<<<gh, 256, 0, stream>>>(obj, hist16);
  }
  k_pick<<<10, 1024, 0, stream>>>(hist16, bstarG, remG, cntg, cnt2);
  {
    dim3 gc(10, 16);
    k_collect<<<gc, 256, 0, stream>>>(obj, bstarG, cntg, cnt2, mainG, LbufG);
  }
  k_seldecode<<<10, 1024, 0, stream>>>(obj, deltas, anchors, mainG, LbufG, cntg, cnt2,
                                       remG, bstarG, boxL, scoreL, nbox, okeyN, ncnt);
  {
    dim3 gm(10, 16, 16);
    k_mask<<<gm, 64, 0, stream>>>(nbox, ncnt, LTG, diagF);
  }
  k_scan<<<10, 256, 0, stream>>>(LTG, diagF, ncnt, keptW);
  k_merge<<<2, 1024, 0, stream>>>(keptW, okeyN, ncnt, boxL, scoreL, out);
}